// Round 1
// baseline (433.507 us; speedup 1.0000x reference)
//
#include <hip/hip_runtime.h>
#include <hip/hip_bf16.h>

// SmoothnessConstraint: out[b,0,:]=x[b,0,:]; out[b,t,:]=out[b,t-1,:]+clip(x[b,t,:]-x[b,t-1,:],-0.5,0.5)
// B=4096, T=256, A=64, fp32. Memory-bound scan along T (stride A), contiguous in A.
// One thread per (b, a4-group-of-4): float4 loads/stores, 256 B contiguous per
// 16-lane quarter-wave, 255-iteration sequential scan with unroll-8 so loads pipeline.

__global__ __launch_bounds__(256) void smoothness_kernel(
    const float* __restrict__ in, float* __restrict__ out) {
    constexpr int T = 256;
    constexpr int A4 = 16;  // A/4 float4s per row

    const int tid = blockIdx.x * blockDim.x + threadIdx.x;   // 0 .. B*A4-1
    const int b   = tid >> 4;
    const int a4  = tid & 15;

    const size_t base = (size_t)b * T * A4 + a4;
    const float4* __restrict__ ip = (const float4*)in + base;
    float4* __restrict__ op       = (float4*)out + base;

    float4 prev = ip[0];   // raw x[t-1]
    float4 acc  = prev;    // reconstructed output
    op[0] = acc;

    #pragma unroll 8
    for (int t = 1; t < T; ++t) {
        float4 cur = ip[t * A4];
        float dx = fminf(fmaxf(cur.x - prev.x, -0.5f), 0.5f);
        float dy = fminf(fmaxf(cur.y - prev.y, -0.5f), 0.5f);
        float dz = fminf(fmaxf(cur.z - prev.z, -0.5f), 0.5f);
        float dw = fminf(fmaxf(cur.w - prev.w, -0.5f), 0.5f);
        acc.x += dx; acc.y += dy; acc.z += dz; acc.w += dw;
        op[t * A4] = acc;
        prev = cur;
    }
}

extern "C" void kernel_launch(void* const* d_in, const int* in_sizes, int n_in,
                              void* d_out, int out_size, void* d_ws, size_t ws_size,
                              hipStream_t stream) {
    const float* in = (const float*)d_in[0];
    float* out = (float*)d_out;

    constexpr int B = 4096, A = 64;
    const int threads = B * (A / 4);          // 65536
    const int block = 256;
    const int grid = threads / block;         // 256

    smoothness_kernel<<<grid, block, 0, stream>>>(in, out);
}